// Round 1
// baseline (1240.535 us; speedup 1.0000x reference)
//
#include <hip/hip_runtime.h>

typedef short v8s __attribute__((ext_vector_type(8)));
typedef float v4f __attribute__((ext_vector_type(4)));

#define BM 64
#define BN 64
#define BK 32
#define LDT 40  // padded LDS row stride (elems): 80B -> 2-way bank aliasing only (free)

__device__ __forceinline__ unsigned short f2bf(float f) {
    unsigned int u = __float_as_uint(f);
    u += 0x7fff + ((u >> 16) & 1);   // RNE
    return (unsigned short)(u >> 16);
}
__device__ __forceinline__ float bf2f(unsigned short h) {
    return __uint_as_float(((unsigned int)h) << 16);
}

union U128 { unsigned short s[8]; uint4 v; };

// ---------------------------------------------------------------------------
// split fp32 -> (bf16 hi, bf16 lo)
__global__ __launch_bounds__(256) void split_f32(const float* __restrict__ x,
                                                 unsigned short* __restrict__ oh,
                                                 unsigned short* __restrict__ ol, int n) {
    int i = blockIdx.x * 256 + threadIdx.x;
    if (i < n) {
        float f = x[i];
        unsigned short h = f2bf(f);
        oh[i] = h;
        ol[i] = f2bf(f - bf2f(h));
    }
}

// ---------------------------------------------------------------------------
// AGG = adj @ H   per batch.  adj fp32 [1024x1024] (split in-kernel),
// H bf16 hi/lo [B*1024 x d].  Output AGG bf16 hi/lo [B*1024 x d].
__global__ __launch_bounds__(256) void agg_gemm(const float* __restrict__ adj,
                                                const unsigned short* __restrict__ hh,
                                                const unsigned short* __restrict__ hl,
                                                unsigned short* __restrict__ oh,
                                                unsigned short* __restrict__ ol, int d) {
    __shared__ __align__(16) unsigned short Ah[BM][LDT], Al[BM][LDT], Bh[BN][LDT], Bl[BN][LDT];
    const int t = threadIdx.x;
    const int b = blockIdx.z;
    const int m0 = blockIdx.x * BM, n0 = blockIdx.y * BN;
    const float* adjb = adj + ((size_t)b << 20);
    const unsigned short* hhb = hh + (size_t)b * 1024 * d;
    const unsigned short* hlb = hl + (size_t)b * 1024 * d;

    const int lane = t & 63, wave = t >> 6;
    const int wm = wave >> 1, wn = wave & 1;
    const int l15 = lane & 15, quad = lane >> 4;
    const int ar = t >> 2, aq = t & 3;          // A staging: row, k-octet
    const int bn = t & 63, bk = (t >> 6) * 8;   // B staging: col, k-base

    v4f acc[2][2] = {};

    for (int kk = 0; kk < 1024; kk += BK) {
        __syncthreads();
        {   // A: adj fp32 -> hi/lo, direct layout [row][k]
            const float* src = adjb + (size_t)(m0 + ar) * 1024 + kk + aq * 8;
            float4 f0 = *(const float4*)src;
            float4 f1 = *(const float4*)(src + 4);
            float f[8] = {f0.x, f0.y, f0.z, f0.w, f1.x, f1.y, f1.z, f1.w};
            U128 uh, ul;
#pragma unroll
            for (int j = 0; j < 8; ++j) {
                unsigned short h = f2bf(f[j]);
                uh.s[j] = h;
                ul.s[j] = f2bf(f[j] - bf2f(h));
            }
            *(uint4*)&Ah[ar][aq * 8] = uh.v;
            *(uint4*)&Al[ar][aq * 8] = ul.v;
        }
        {   // B: H bf16, transpose k-major -> [n][k]
            U128 uh, ul;
#pragma unroll
            for (int j = 0; j < 8; ++j) {
                size_t off = (size_t)(kk + bk + j) * d + n0 + bn;
                uh.s[j] = hhb[off];
                ul.s[j] = hlb[off];
            }
            *(uint4*)&Bh[bn][bk] = uh.v;
            *(uint4*)&Bl[bn][bk] = ul.v;
        }
        __syncthreads();
        v8s a_hi[2], a_lo[2], b_hi[2], b_lo[2];
#pragma unroll
        for (int i = 0; i < 2; ++i) {
            int arow = wm * 32 + i * 16 + l15;
            a_hi[i] = *(const v8s*)&Ah[arow][quad * 8];
            a_lo[i] = *(const v8s*)&Al[arow][quad * 8];
            int brow = wn * 32 + i * 16 + l15;
            b_hi[i] = *(const v8s*)&Bh[brow][quad * 8];
            b_lo[i] = *(const v8s*)&Bl[brow][quad * 8];
        }
#pragma unroll
        for (int mi = 0; mi < 2; ++mi)
#pragma unroll
            for (int ni = 0; ni < 2; ++ni) {
                acc[mi][ni] = __builtin_amdgcn_mfma_f32_16x16x32_bf16(a_hi[mi], b_hi[ni], acc[mi][ni], 0, 0, 0);
                acc[mi][ni] = __builtin_amdgcn_mfma_f32_16x16x32_bf16(a_hi[mi], b_lo[ni], acc[mi][ni], 0, 0, 0);
                acc[mi][ni] = __builtin_amdgcn_mfma_f32_16x16x32_bf16(a_lo[mi], b_hi[ni], acc[mi][ni], 0, 0, 0);
            }
    }
    // epilogue: split-store hi/lo
#pragma unroll
    for (int mi = 0; mi < 2; ++mi)
#pragma unroll
        for (int ni = 0; ni < 2; ++ni) {
            int n = n0 + wn * 32 + ni * 16 + l15;
#pragma unroll
            for (int r = 0; r < 4; ++r) {
                int m = m0 + wm * 32 + mi * 16 + quad * 4 + r;
                float v = acc[mi][ni][r];
                size_t o = (size_t)(b * 1024 + m) * d + n;
                unsigned short h = f2bf(v);
                oh[o] = h;
                ol[o] = f2bf(v - bf2f(h));
            }
        }
}

// ---------------------------------------------------------------------------
// Hnext = act( H @ W[0:K1] + AGG @ W[K1:K1+K2] + bias ), M = 32768 flat.
// ACT: 0 none, 1 relu, 2 prelu(alpha)
template <int ACT>
__global__ __launch_bounds__(256) void dense_gemm(const unsigned short* __restrict__ a1h,
                                                  const unsigned short* __restrict__ a1l,
                                                  const unsigned short* __restrict__ a2h,
                                                  const unsigned short* __restrict__ a2l,
                                                  const float* __restrict__ W,
                                                  const float* __restrict__ bias,
                                                  const float* __restrict__ alpha,
                                                  unsigned short* __restrict__ oh,
                                                  unsigned short* __restrict__ ol,
                                                  int Nout, int K1, int K2) {
    __shared__ __align__(16) unsigned short Ah[BM][LDT], Al[BM][LDT], Bh[BN][LDT], Bl[BN][LDT];
    const int t = threadIdx.x;
    const int m0 = blockIdx.x * BM, n0 = blockIdx.y * BN;
    const int lane = t & 63, wave = t >> 6;
    const int wm = wave >> 1, wn = wave & 1;
    const int l15 = lane & 15, quad = lane >> 4;
    const int ar = t >> 2, aq = t & 3;
    const int bn = t & 63, bk = (t >> 6) * 8;

    v4f acc[2][2] = {};

    for (int chunk = 0; chunk < 2; ++chunk) {
        const unsigned short* ah = chunk ? a2h : a1h;
        const unsigned short* al = chunk ? a2l : a1l;
        const int K = chunk ? K2 : K1;
        const int krow0 = chunk ? K1 : 0;
        if (K == 0) continue;
        for (int kk = 0; kk < K; kk += BK) {
            __syncthreads();
            {   // A: bf16 hi/lo direct copy
                const size_t off = (size_t)(m0 + ar) * K + kk + aq * 8;
                *(uint4*)&Ah[ar][aq * 8] = *(const uint4*)(ah + off);
                *(uint4*)&Al[ar][aq * 8] = *(const uint4*)(al + off);
            }
            {   // B: W fp32 -> hi/lo, transpose into [n][k]
                U128 uh, ul;
#pragma unroll
                for (int j = 0; j < 8; ++j) {
                    float w = W[(size_t)(krow0 + kk + bk + j) * Nout + n0 + bn];
                    unsigned short h = f2bf(w);
                    uh.s[j] = h;
                    ul.s[j] = f2bf(w - bf2f(h));
                }
                *(uint4*)&Bh[bn][bk] = uh.v;
                *(uint4*)&Bl[bn][bk] = ul.v;
            }
            __syncthreads();
            v8s a_hi[2], a_lo[2], b_hi[2], b_lo[2];
#pragma unroll
            for (int i = 0; i < 2; ++i) {
                int arow = wm * 32 + i * 16 + l15;
                a_hi[i] = *(const v8s*)&Ah[arow][quad * 8];
                a_lo[i] = *(const v8s*)&Al[arow][quad * 8];
                int brow = wn * 32 + i * 16 + l15;
                b_hi[i] = *(const v8s*)&Bh[brow][quad * 8];
                b_lo[i] = *(const v8s*)&Bl[brow][quad * 8];
            }
#pragma unroll
            for (int mi = 0; mi < 2; ++mi)
#pragma unroll
                for (int ni = 0; ni < 2; ++ni) {
                    acc[mi][ni] = __builtin_amdgcn_mfma_f32_16x16x32_bf16(a_hi[mi], b_hi[ni], acc[mi][ni], 0, 0, 0);
                    acc[mi][ni] = __builtin_amdgcn_mfma_f32_16x16x32_bf16(a_hi[mi], b_lo[ni], acc[mi][ni], 0, 0, 0);
                    acc[mi][ni] = __builtin_amdgcn_mfma_f32_16x16x32_bf16(a_lo[mi], b_hi[ni], acc[mi][ni], 0, 0, 0);
                }
        }
    }
#pragma unroll
    for (int mi = 0; mi < 2; ++mi)
#pragma unroll
        for (int ni = 0; ni < 2; ++ni) {
            int n = n0 + wn * 32 + ni * 16 + l15;
            float bv = bias[n];
            float av = (ACT == 2) ? alpha[n] : 0.f;
#pragma unroll
            for (int r = 0; r < 4; ++r) {
                int m = m0 + wm * 32 + mi * 16 + quad * 4 + r;
                float v = acc[mi][ni][r] + bv;
                if (ACT == 1) v = v > 0.f ? v : 0.f;
                if (ACT == 2) v = v > 0.f ? v : av * v;
                size_t o = (size_t)m * Nout + n;
                unsigned short h = f2bf(v);
                oh[o] = h;
                ol[o] = f2bf(v - bf2f(h));
            }
        }
}

// ---------------------------------------------------------------------------
// pred = H5 @ cW2 + cb2, Nout=2, K=256, pure fp32 accumulation.
__global__ __launch_bounds__(256) void final_gemm(const unsigned short* __restrict__ hh,
                                                  const unsigned short* __restrict__ hl,
                                                  const float* __restrict__ W,
                                                  const float* __restrict__ bias,
                                                  float* __restrict__ out) {
    const int t = threadIdx.x;
    const int m = blockIdx.x * 64 + (t >> 2);
    const int kq = (t & 3) * 64;
    const unsigned short* ph = hh + (size_t)m * 256 + kq;
    const unsigned short* pl = hl + (size_t)m * 256 + kq;
    float a0 = 0.f, a1 = 0.f;
#pragma unroll
    for (int i = 0; i < 8; ++i) {
        uint4 vh = *(const uint4*)(ph + i * 8);
        uint4 vl = *(const uint4*)(pl + i * 8);
        const unsigned short* sh = (const unsigned short*)&vh;
        const unsigned short* sl = (const unsigned short*)&vl;
#pragma unroll
        for (int j = 0; j < 8; ++j) {
            int k = kq + i * 8 + j;
            float h = bf2f(sh[j]) + bf2f(sl[j]);
            a0 += h * W[k * 2];
            a1 += h * W[k * 2 + 1];
        }
    }
    a0 += __shfl_down(a0, 2); a0 += __shfl_down(a0, 1);
    a1 += __shfl_down(a1, 2); a1 += __shfl_down(a1, 1);
    if ((t & 3) == 0) {
        out[(size_t)m * 2] = a0 + bias[0];
        out[(size_t)m * 2 + 1] = a1 + bias[1];
    }
}

// ---------------------------------------------------------------------------
extern "C" void kernel_launch(void* const* d_in, const int* in_sizes, int n_in,
                              void* d_out, int out_size, void* d_ws, size_t ws_size,
                              hipStream_t stream) {
    const float* x   = (const float*)d_in[0];
    const float* adj = (const float*)d_in[1];
    const float* W1  = (const float*)d_in[2];
    const float* b1  = (const float*)d_in[3];
    const float* W2  = (const float*)d_in[4];
    const float* b2  = (const float*)d_in[5];
    const float* W3  = (const float*)d_in[6];
    const float* b3  = (const float*)d_in[7];
    const float* W4  = (const float*)d_in[8];
    const float* b4  = (const float*)d_in[9];
    const float* cW1 = (const float*)d_in[10];
    const float* cb1 = (const float*)d_in[11];
    const float* alp = (const float*)d_in[12];
    const float* cW2 = (const float*)d_in[13];
    const float* cb2 = (const float*)d_in[14];
    float* out = (float*)d_out;

    const size_t actE = 32ull * 1024 * 512;  // 16,777,216 elems per array
    unsigned short* Ah = (unsigned short*)d_ws;
    unsigned short* Al = Ah + actE;
    unsigned short* Bh = Al + actE;
    unsigned short* Bl = Bh + actE;
    unsigned short* Ch = Bl + actE;
    unsigned short* Cl = Ch + actE;

    dim3 blk(256);

    // 1. split x -> A (d=256)
    split_f32<<<32768, blk, 0, stream>>>(x, Ah, Al, 32 * 1024 * 256);
    // 2. AGG1 = adj @ x -> B (256)
    agg_gemm<<<dim3(16, 4, 32), blk, 0, stream>>>(adj, Ah, Al, Bh, Bl, 256);
    // 3. H1 = relu([x|AGG1] @ W1 + b1) -> C (512)
    dense_gemm<1><<<dim3(512, 8), blk, 0, stream>>>(Ah, Al, Bh, Bl, W1, b1, nullptr, Ch, Cl, 512, 256, 256);
    // 4. AGG2 = adj @ H1 -> A (512)
    agg_gemm<<<dim3(16, 8, 32), blk, 0, stream>>>(adj, Ch, Cl, Ah, Al, 512);
    // 5. H2 -> B (512)
    dense_gemm<1><<<dim3(512, 8), blk, 0, stream>>>(Ch, Cl, Ah, Al, W2, b2, nullptr, Bh, Bl, 512, 512, 512);
    // 6. AGG3 = adj @ H2 -> A (512)
    agg_gemm<<<dim3(16, 8, 32), blk, 0, stream>>>(adj, Bh, Bl, Ah, Al, 512);
    // 7. H3 -> C (256)
    dense_gemm<1><<<dim3(512, 4), blk, 0, stream>>>(Bh, Bl, Ah, Al, W3, b3, nullptr, Ch, Cl, 256, 512, 512);
    // 8. AGG4 = adj @ H3 -> B (256)
    agg_gemm<<<dim3(16, 4, 32), blk, 0, stream>>>(adj, Ch, Cl, Bh, Bl, 256);
    // 9. H4 -> A (256)
    dense_gemm<1><<<dim3(512, 4), blk, 0, stream>>>(Ch, Cl, Bh, Bl, W4, b4, nullptr, Ah, Al, 256, 256, 256);
    // 10. H5 = prelu(H4 @ cW1 + cb1) -> C (256)
    dense_gemm<2><<<dim3(512, 4), blk, 0, stream>>>(Ah, Al, nullptr, nullptr, cW1, cb1, alp, Ch, Cl, 256, 256, 0);
    // 11. pred = H5 @ cW2 + cb2 -> out
    final_gemm<<<512, blk, 0, stream>>>(Ch, Cl, cW2, cb2, out);
}

// Round 2
// 1070.860 us; speedup vs baseline: 1.1584x; 1.1584x over previous
//
#include <hip/hip_runtime.h>

typedef short v8s __attribute__((ext_vector_type(8)));
typedef float v4f __attribute__((ext_vector_type(4)));

#define BMT 128
#define BNT 128
#define BKT 32

__device__ __forceinline__ unsigned short f2bf(float f) {
    unsigned int u = __float_as_uint(f);
    u += 0x7fff + ((u >> 16) & 1);   // RNE
    return (unsigned short)(u >> 16);
}
__device__ __forceinline__ float bf2f(unsigned short h) {
    return __uint_as_float(((unsigned int)h) << 16);
}

union U128 { unsigned short s[8]; uint4 v; };

// async 16B global -> LDS (wave-uniform LDS base + lane*16 implicit)
__device__ __forceinline__ void gld16(const unsigned short* g, unsigned short* l) {
    __builtin_amdgcn_global_load_lds((const __attribute__((address_space(1))) void*)g,
                                     (__attribute__((address_space(3))) void*)l, 16, 0, 0);
}

// ---------------------------------------------------------------------------
// split fp32 -> (bf16 hi, bf16 lo), vectorized
__global__ __launch_bounds__(256) void split_pair(const float* __restrict__ x,
                                                  unsigned short* __restrict__ oh,
                                                  unsigned short* __restrict__ ol, int n4) {
    int i = blockIdx.x * 256 + threadIdx.x;
    if (i < n4) {
        float4 f = ((const float4*)x)[i];
        float fv[4] = {f.x, f.y, f.z, f.w};
        ushort4 h, l;
        unsigned short* hp = (unsigned short*)&h;
        unsigned short* lp = (unsigned short*)&l;
#pragma unroll
        for (int j = 0; j < 4; ++j) {
            unsigned short hh = f2bf(fv[j]);
            hp[j] = hh;
            lp[j] = f2bf(fv[j] - bf2f(hh));
        }
        ((ushort4*)oh)[i] = h;
        ((ushort4*)ol)[i] = l;
    }
}

// split + transpose: W fp32 [R][C] -> WT hi/lo bf16 [C][R]
__global__ __launch_bounds__(256) void tsplit(const float* __restrict__ W,
                                              unsigned short* __restrict__ th,
                                              unsigned short* __restrict__ tl, int R, int C) {
    int e = blockIdx.x * 256 + threadIdx.x;
    if (e < R * C) {
        int k = e / C, n = e - k * C;
        float w = W[e];
        unsigned short h = f2bf(w);
        size_t o = (size_t)n * R + k;
        th[o] = h;
        tl[o] = f2bf(w - bf2f(h));
    }
}

// ---------------------------------------------------------------------------
// 128x128x32 split-bf16 GEMM.
// AMODE: 0 = pre-split bf16 hi/lo [M][K] via global_load_lds (swizzled LDS)
//        1 = fp32 source, split in-kernel (padded LDS)        [adj fallback]
// BMODE: 0 = pre-split transposed [N][Ktot] via global_load_lds (swizzled)
//        1 = gather from normal hi/lo [K][N] (padded LDS)      [H for agg]
// ACT: 0 none/no bias, 1 bias+relu, 2 bias+prelu
template <int ACT, bool TWO, int AMODE, int BMODE>
__global__ __launch_bounds__(256) void gemm128(
    const void* a1a, const void* a1b,
    const unsigned short* __restrict__ a2h, const unsigned short* __restrict__ a2l,
    int K1, int K2,
    const unsigned short* __restrict__ bh_, const unsigned short* __restrict__ bl_, int ldb,
    const float* __restrict__ bias, const float* __restrict__ alpha,
    unsigned short* __restrict__ oh, unsigned short* __restrict__ ol, int Nout,
    size_t aZStride, size_t bZStride, int cZRows)
{
    constexpr int LA = (AMODE == 0) ? 32 : 40;
    constexpr int LB = (BMODE == 0) ? 32 : 40;
    __shared__ __align__(16) unsigned short Ash[BMT * LA], Asl[BMT * LA];
    __shared__ __align__(16) unsigned short Bsh[BNT * LB], Bsl[BNT * LB];

    const int t = threadIdx.x;
    const int lane = t & 63, wave = t >> 6;
    const int wm = wave >> 1, wn = wave & 1;
    const int l15 = lane & 15, quad = lane >> 4;
    const int zb = blockIdx.z;
    const int n0 = blockIdx.x * BNT;
    const int m0 = blockIdx.y * BMT;

    v4f acc[4][4] = {};

    const int nch = TWO ? 2 : 1;
    for (int ch = 0; ch < nch; ++ch) {
        const int K = (TWO && ch) ? K2 : K1;
        const int kr0 = (TWO && ch) ? K1 : 0;
        const unsigned short* ah = nullptr;
        const unsigned short* al = nullptr;
        const float* af = nullptr;
        if constexpr (AMODE == 0) {
            ah = (ch ? a2h : (const unsigned short*)a1a) + (size_t)zb * aZStride;
            al = (ch ? a2l : (const unsigned short*)a1b) + (size_t)zb * aZStride;
        } else {
            af = (const float*)a1a + (size_t)zb * aZStride;
        }

        for (int kk = 0; kk < K; kk += BKT) {
            __syncthreads();
            // ---- stage A
            if constexpr (AMODE == 0) {
#pragma unroll
                for (int i = 0; i < 2; ++i) {
                    int s = i * 256 + t;
                    int row = s >> 2;
                    int cg = (s & 3) ^ ((s >> 3) & 3);           // chunk swizzle
                    size_t go = (size_t)(m0 + row) * K + kk + cg * 8;
                    int ls = (i * 256 + (t & ~63)) * 8;          // wave-uniform base
                    gld16(ah + go, &Ash[ls]);
                    gld16(al + go, &Asl[ls]);
                }
            } else {
#pragma unroll
                for (int i = 0; i < 2; ++i) {
                    int cid = i * 256 + t;
                    int row = cid >> 2, c = cid & 3;
                    const float* src = af + (size_t)(m0 + row) * K + kk + c * 8;
                    float4 f0 = *(const float4*)src;
                    float4 f1 = *(const float4*)(src + 4);
                    float fv[8] = {f0.x, f0.y, f0.z, f0.w, f1.x, f1.y, f1.z, f1.w};
                    U128 uh, ul;
#pragma unroll
                    for (int j = 0; j < 8; ++j) {
                        unsigned short h = f2bf(fv[j]);
                        uh.s[j] = h;
                        ul.s[j] = f2bf(fv[j] - bf2f(h));
                    }
                    *(uint4*)&Ash[row * LA + c * 8] = uh.v;
                    *(uint4*)&Asl[row * LA + c * 8] = ul.v;
                }
            }
            // ---- stage B
            if constexpr (BMODE == 0) {
#pragma unroll
                for (int i = 0; i < 2; ++i) {
                    int s = i * 256 + t;
                    int row = s >> 2;
                    int cg = (s & 3) ^ ((s >> 3) & 3);
                    size_t go = (size_t)(n0 + row) * ldb + kr0 + kk + cg * 8;
                    int ls = (i * 256 + (t & ~63)) * 8;
                    gld16(bh_ + go, &Bsh[ls]);
                    gld16(bl_ + go, &Bsl[ls]);
                }
            } else {
                const unsigned short* gh = bh_ + (size_t)zb * bZStride;
                const unsigned short* gl = bl_ + (size_t)zb * bZStride;
                int bn = t & 127, kb = (t >> 7) * 16;
                U128 h0, h1, l0, l1;
#pragma unroll
                for (int j = 0; j < 8; ++j) {
                    size_t o = (size_t)(kk + kb + j) * ldb + n0 + bn;
                    h0.s[j] = gh[o];
                    l0.s[j] = gl[o];
                }
#pragma unroll
                for (int j = 0; j < 8; ++j) {
                    size_t o = (size_t)(kk + kb + 8 + j) * ldb + n0 + bn;
                    h1.s[j] = gh[o];
                    l1.s[j] = gl[o];
                }
                *(uint4*)&Bsh[bn * LB + kb] = h0.v;
                *(uint4*)&Bsh[bn * LB + kb + 8] = h1.v;
                *(uint4*)&Bsl[bn * LB + kb] = l0.v;
                *(uint4*)&Bsl[bn * LB + kb + 8] = l1.v;
            }
            __syncthreads();
            // ---- compute
            v8s ahf[4], alf[4];
#pragma unroll
            for (int mi = 0; mi < 4; ++mi) {
                int row = wm * 64 + mi * 16 + l15;
                int off;
                if constexpr (AMODE == 0) off = row * LA + ((quad ^ ((row >> 1) & 3)) * 8);
                else                      off = row * LA + quad * 8;
                ahf[mi] = *(const v8s*)&Ash[off];
                alf[mi] = *(const v8s*)&Asl[off];
            }
#pragma unroll
            for (int ni = 0; ni < 4; ++ni) {
                int row = wn * 64 + ni * 16 + l15;
                int off;
                if constexpr (BMODE == 0) off = row * LB + ((quad ^ ((row >> 1) & 3)) * 8);
                else                      off = row * LB + quad * 8;
                v8s bhf = *(const v8s*)&Bsh[off];
                v8s blf = *(const v8s*)&Bsl[off];
#pragma unroll
                for (int mi = 0; mi < 4; ++mi) {
                    acc[mi][ni] = __builtin_amdgcn_mfma_f32_16x16x32_bf16(ahf[mi], bhf, acc[mi][ni], 0, 0, 0);
                    acc[mi][ni] = __builtin_amdgcn_mfma_f32_16x16x32_bf16(ahf[mi], blf, acc[mi][ni], 0, 0, 0);
                    acc[mi][ni] = __builtin_amdgcn_mfma_f32_16x16x32_bf16(alf[mi], bhf, acc[mi][ni], 0, 0, 0);
                }
            }
        }
    }

    // ---- epilogue: bias/act + split-store hi/lo
    const size_t crow0 = (size_t)zb * cZRows + m0;
#pragma unroll
    for (int ni = 0; ni < 4; ++ni) {
        int n = n0 + wn * 64 + ni * 16 + l15;
        float bv = (ACT > 0) ? bias[n] : 0.f;
        float av = (ACT == 2) ? alpha[n] : 0.f;
#pragma unroll
        for (int mi = 0; mi < 4; ++mi) {
#pragma unroll
            for (int r = 0; r < 4; ++r) {
                int m = wm * 64 + mi * 16 + quad * 4 + r;
                float v = acc[mi][ni][r] + bv;
                if (ACT == 1) v = v > 0.f ? v : 0.f;
                if (ACT == 2) v = v > 0.f ? v : av * v;
                size_t o = (crow0 + m) * (size_t)Nout + n;
                unsigned short h = f2bf(v);
                oh[o] = h;
                ol[o] = f2bf(v - bf2f(h));
            }
        }
    }
}

// ---------------------------------------------------------------------------
// pred = H5 @ cW2 + cb2, Nout=2, K=256, fp32 accumulation
__global__ __launch_bounds__(256) void final_gemm(const unsigned short* __restrict__ hh,
                                                  const unsigned short* __restrict__ hl,
                                                  const float* __restrict__ W,
                                                  const float* __restrict__ bias,
                                                  float* __restrict__ out) {
    const int t = threadIdx.x;
    const int m = blockIdx.x * 64 + (t >> 2);
    const int kq = (t & 3) * 64;
    const unsigned short* ph = hh + (size_t)m * 256 + kq;
    const unsigned short* pl = hl + (size_t)m * 256 + kq;
    float a0 = 0.f, a1 = 0.f;
#pragma unroll
    for (int i = 0; i < 8; ++i) {
        uint4 vh = *(const uint4*)(ph + i * 8);
        uint4 vl = *(const uint4*)(pl + i * 8);
        const unsigned short* sh = (const unsigned short*)&vh;
        const unsigned short* sl = (const unsigned short*)&vl;
#pragma unroll
        for (int j = 0; j < 8; ++j) {
            int k = kq + i * 8 + j;
            float h = bf2f(sh[j]) + bf2f(sl[j]);
            a0 += h * W[k * 2];
            a1 += h * W[k * 2 + 1];
        }
    }
    a0 += __shfl_down(a0, 2); a0 += __shfl_down(a0, 1);
    a1 += __shfl_down(a1, 2); a1 += __shfl_down(a1, 1);
    if ((t & 3) == 0) {
        out[(size_t)m * 2] = a0 + bias[0];
        out[(size_t)m * 2 + 1] = a1 + bias[1];
    }
}

// ---------------------------------------------------------------------------
extern "C" void kernel_launch(void* const* d_in, const int* in_sizes, int n_in,
                              void* d_out, int out_size, void* d_ws, size_t ws_size,
                              hipStream_t stream) {
    const float* x   = (const float*)d_in[0];
    const float* adj = (const float*)d_in[1];
    const float* W1  = (const float*)d_in[2];
    const float* b1  = (const float*)d_in[3];
    const float* W2  = (const float*)d_in[4];
    const float* b2  = (const float*)d_in[5];
    const float* W3  = (const float*)d_in[6];
    const float* b3  = (const float*)d_in[7];
    const float* W4  = (const float*)d_in[8];
    const float* b4  = (const float*)d_in[9];
    const float* cW1 = (const float*)d_in[10];
    const float* cb1 = (const float*)d_in[11];
    const float* alp = (const float*)d_in[12];
    const float* cW2 = (const float*)d_in[13];
    const float* cb2 = (const float*)d_in[14];
    float* out = (float*)d_out;

    const size_t P = 32768ull * 512;           // 16,777,216 elems per plane
    const size_t WT_TOT = 1245184;             // sum of all transposed weight elems
    const size_t ADJ = 32ull * 1024 * 1024;    // 33,554,432

    unsigned short* N1h = (unsigned short*)d_ws;
    unsigned short* N1l = N1h + P;
    unsigned short* N2h = N1l + P;
    unsigned short* N2l = N2h + P;
    unsigned short* N3h = N2l + P;
    unsigned short* N3l = N3h + P;
    unsigned short* WTh = N3l + P;
    unsigned short* WTl = WTh + WT_TOT;
    unsigned short* SAh = WTl + WT_TOT;
    unsigned short* SAl = SAh + ADJ;

    const size_t o1 = 0, o2 = 262144, o3 = 786432, o4 = 1048576, o5 = 1179648;
    const bool preAdj = ws_size >= (6 * P + 2 * WT_TOT + 2 * ADJ) * sizeof(unsigned short);

    dim3 blk(256);

    // weight / input pre-splits
    split_pair<<<8192, blk, 0, stream>>>(x, N1h, N1l, (int)(32ull * 1024 * 256 / 4));
    tsplit<<<1024, blk, 0, stream>>>(W1,  WTh + o1, WTl + o1, 512, 512);
    tsplit<<<2048, blk, 0, stream>>>(W2,  WTh + o2, WTl + o2, 1024, 512);
    tsplit<<<1024, blk, 0, stream>>>(W3,  WTh + o3, WTl + o3, 1024, 256);
    tsplit<<<512,  blk, 0, stream>>>(W4,  WTh + o4, WTl + o4, 512, 256);
    tsplit<<<256,  blk, 0, stream>>>(cW1, WTh + o5, WTl + o5, 256, 256);
    if (preAdj)
        split_pair<<<32768, blk, 0, stream>>>(adj, SAh, SAl, (int)(ADJ / 4));

    // agg1 = adj @ x (d=256) -> N2
    if (preAdj)
        gemm128<0, false, 0, 1><<<dim3(2, 8, 32), blk, 0, stream>>>(
            SAh, SAl, nullptr, nullptr, 1024, 0, N1h, N1l, 256, nullptr, nullptr,
            N2h, N2l, 256, (size_t)1 << 20, 1024ull * 256, 1024);
    else
        gemm128<0, false, 1, 1><<<dim3(2, 8, 32), blk, 0, stream>>>(
            adj, nullptr, nullptr, nullptr, 1024, 0, N1h, N1l, 256, nullptr, nullptr,
            N2h, N2l, 256, (size_t)1 << 20, 1024ull * 256, 1024);
    // dense1 = relu([x|AGG1] @ W1 + b1) (N=512) -> N3
    gemm128<1, true, 0, 0><<<dim3(4, 256, 1), blk, 0, stream>>>(
        N1h, N1l, N2h, N2l, 256, 256, WTh + o1, WTl + o1, 512, b1, nullptr,
        N3h, N3l, 512, 0, 0, 0);
    // agg2 = adj @ H1 (d=512) -> N1
    if (preAdj)
        gemm128<0, false, 0, 1><<<dim3(4, 8, 32), blk, 0, stream>>>(
            SAh, SAl, nullptr, nullptr, 1024, 0, N3h, N3l, 512, nullptr, nullptr,
            N1h, N1l, 512, (size_t)1 << 20, 1024ull * 512, 1024);
    else
        gemm128<0, false, 1, 1><<<dim3(4, 8, 32), blk, 0, stream>>>(
            adj, nullptr, nullptr, nullptr, 1024, 0, N3h, N3l, 512, nullptr, nullptr,
            N1h, N1l, 512, (size_t)1 << 20, 1024ull * 512, 1024);
    // dense2 (N=512) -> N2
    gemm128<1, true, 0, 0><<<dim3(4, 256, 1), blk, 0, stream>>>(
        N3h, N3l, N1h, N1l, 512, 512, WTh + o2, WTl + o2, 1024, b2, nullptr,
        N2h, N2l, 512, 0, 0, 0);
    // agg3 = adj @ H2 (d=512) -> N1
    if (preAdj)
        gemm128<0, false, 0, 1><<<dim3(4, 8, 32), blk, 0, stream>>>(
            SAh, SAl, nullptr, nullptr, 1024, 0, N2h, N2l, 512, nullptr, nullptr,
            N1h, N1l, 512, (size_t)1 << 20, 1024ull * 512, 1024);
    else
        gemm128<0, false, 1, 1><<<dim3(4, 8, 32), blk, 0, stream>>>(
            adj, nullptr, nullptr, nullptr, 1024, 0, N2h, N2l, 512, nullptr, nullptr,
            N1h, N1l, 512, (size_t)1 << 20, 1024ull * 512, 1024);
    // dense3 (N=256) -> N3
    gemm128<1, true, 0, 0><<<dim3(2, 256, 1), blk, 0, stream>>>(
        N2h, N2l, N1h, N1l, 512, 512, WTh + o3, WTl + o3, 1024, b3, nullptr,
        N3h, N3l, 256, 0, 0, 0);
    // agg4 = adj @ H3 (d=256) -> N1
    if (preAdj)
        gemm128<0, false, 0, 1><<<dim3(2, 8, 32), blk, 0, stream>>>(
            SAh, SAl, nullptr, nullptr, 1024, 0, N3h, N3l, 256, nullptr, nullptr,
            N1h, N1l, 256, (size_t)1 << 20, 1024ull * 256, 1024);
    else
        gemm128<0, false, 1, 1><<<dim3(2, 8, 32), blk, 0, stream>>>(
            adj, nullptr, nullptr, nullptr, 1024, 0, N3h, N3l, 256, nullptr, nullptr,
            N1h, N1l, 256, (size_t)1 << 20, 1024ull * 256, 1024);
    // dense4 (N=256) -> N2
    gemm128<1, true, 0, 0><<<dim3(2, 256, 1), blk, 0, stream>>>(
        N3h, N3l, N1h, N1l, 256, 256, WTh + o4, WTl + o4, 512, b4, nullptr,
        N2h, N2l, 256, 0, 0, 0);
    // cls1 = prelu(H4 @ cW1 + cb1) (N=256) -> N3
    gemm128<2, false, 0, 0><<<dim3(2, 256, 1), blk, 0, stream>>>(
        N2h, N2l, nullptr, nullptr, 256, 0, WTh + o5, WTl + o5, 256, cb1, alp,
        N3h, N3l, 256, 0, 0, 0);
    // final
    final_gemm<<<512, blk, 0, stream>>>(N3h, N3l, cW2, cb2, out);
}